// Round 12
// baseline (55.130 us; speedup 1.0000x reference)
//
#include <hip/hip_runtime.h>
#include <math.h>

#define NPTS 87296
#define NCLS 16
#define KPOS 256
#define KHN  2048
#define TILES 341           // NPTS / 256 exactly
#define CAP  4096           // compacted-candidate capacity (slow path beyond)
#define PI_F   3.14159265358979323846f
#define HPI_F  1.57079632679489661923f

struct InPtrs { const float* p[40]; };
// input index = pre*20 + lvl*4 + {cls:0, box:1, ang:2, ctr:3}; pre: t=0, s=1

// ---------------- persistent device scratch (rewritten every call) ----------------
__device__ float g_max_vals[NPTS];
__device__ float g_sig_tiou[NPTS];
__device__ float g_sig_cls_max[NPTS];
__device__ int   g_class_ind[NPTS];
__device__ int   g_pos_mask[NPTS];
__device__ int   g_hn_mask[NPTS];
__device__ int   g_hnflag[NPTS];
__device__ float g_loc_targets[NPTS * 5]; // only hn slots are written/read
__device__ float g_bsum[TILES];
__device__ float g_bsumsq[TILES];
__device__ int   g_bcnt[TILES];
__device__ int   g_bpos[TILES];
__device__ int   g_bhn[TILES];
__device__ float g_thresh;
__device__ int   g_tp, g_thn, g_slow;
__device__ int   g_pos_cand[CAP];
__device__ int   g_hn_cand[CAP];
// coalesced decoded-candidate arrays (fast path)
__device__ float g_pos_bbox[KPOS * 5];
__device__ float g_pos_cor[KPOS * 8];
__device__ float g_pos_area[KPOS];
__device__ float g_pos_scale[KPOS];
__device__ int   g_pos_class[KPOS];
__device__ float g_pv[KPOS];
__device__ float g_hn_px[KHN];
__device__ float g_hn_py[KHN];
__device__ float g_hn_cor[KHN * 8];
__device__ float g_hn_area[KHN];
__device__ float g_hn_scale[KHN];
__device__ int   g_hn_class[KHN];
__device__ float g_partials[TILES * 6];

// ---------------- helpers ----------------
__device__ __forceinline__ float sigmoidf(float x) {
  if (x >= 0.f) return 1.f / (1.f + expf(-x));
  float e = expf(x);
  return e / (1.f + e);
}
__device__ __forceinline__ float crs(float ax, float ay, float bx, float by) {
  return ax * by - ay * bx;
}
__device__ __forceinline__ float mod_pos(float x, float y) {
  float r = fmodf(x, y);
  if (r < 0.f) r += y;
  return r;
}
// monotonic pseudo-angle: strictly increasing map of atan2(dy,dx) -> (-2,2]
__device__ __forceinline__ float pseudo_ang(float dx, float dy) {
  float den = fabsf(dx) + fabsf(dy);
  if (den == 0.f) return 0.f;         // matches atan2(0,0)=0 tie class
  return copysignf(1.f - dx / den, dy);
}
__device__ __forceinline__ void point_info(int n, int& lvl, int& idx, int& hw,
                                           float& px, float& py) {
  int off, wsh; float stride;
  if (n < 65536)      { lvl = 0; off = 0;     wsh = 8; stride = 8.f;   hw = 65536; }
  else if (n < 81920) { lvl = 1; off = 65536; wsh = 7; stride = 16.f;  hw = 16384; }
  else if (n < 86016) { lvl = 2; off = 81920; wsh = 6; stride = 32.f;  hw = 4096; }
  else if (n < 87040) { lvl = 3; off = 86016; wsh = 5; stride = 64.f;  hw = 1024; }
  else                { lvl = 4; off = 87040; wsh = 4; stride = 128.f; hw = 256; }
  idx = n - off;
  int y = idx >> wsh, x = idx & ((1 << wsh) - 1);
  px = ((float)x + 0.5f) * stride;
  py = ((float)y + 0.5f) * stride;
}

// ---------------- radix select paths (rare; block-local, outputs may be LDS) ----------------
#define MASK_ALL 0
#define MASK_POS 1
#define MASK_HN  2
__device__ __forceinline__ int sel_mask(int mode, int n) {
  return mode == MASK_ALL ? 1 : (mode == MASK_POS ? g_pos_mask[n] : g_hn_mask[n]);
}

__device__ void radix_select_mask(int mode, int K, int* out_idx, int* out_valid, float* out_val,
                                  int* hist, int* scan_a, int* scan_b, int* sh) {
  int tid = threadIdx.x;
  int c = 0;
  for (int n = tid; n < NPTS; n += 256) if (sel_mask(mode, n)) c++;
  scan_a[tid] = c; __syncthreads();
  for (int st = 128; st > 0; st >>= 1) {
    if (tid < st) scan_a[tid] += scan_a[tid + st];
    __syncthreads();
  }
  int total = scan_a[0];
  __syncthreads();

  unsigned kth = 0u;
  if (total > K) {
    unsigned prefix = 0; int rem = K;
    for (int pass = 0; pass < 4; pass++) {
      int shift = 24 - 8 * pass;
      hist[tid] = 0;
      __syncthreads();
      for (int n = tid; n < NPTS; n += 256) {
        if (sel_mask(mode, n)) {
          unsigned k = __float_as_uint(g_max_vals[n]);
          if (pass == 0 || ((k >> (shift + 8)) == prefix))
            atomicAdd(&hist[(k >> shift) & 255], 1);
        }
      }
      __syncthreads();
      if (tid == 0) {
        int cum = 0, b = 255;
        for (; b > 0; b--) {
          if (cum + hist[b] >= rem) break;
          cum += hist[b];
        }
        sh[0] = (int)((prefix << 8) | (unsigned)b);
        sh[1] = rem - cum;
      }
      __syncthreads();
      prefix = (unsigned)sh[0]; rem = sh[1];
      __syncthreads();
    }
    kth = prefix;
  }

  const int chunk = (NPTS + 255) / 256;
  int start = tid * chunk; if (start > NPTS) start = NPTS;
  int end = start + chunk; if (end > NPTS) end = NPTS;
  int cgt = 0, ceq = 0;
  for (int n = start; n < end; n++) {
    if (sel_mask(mode, n)) {
      unsigned k = __float_as_uint(g_max_vals[n]);
      if (k > kth) cgt++;
      else if (k == kth) ceq++;
    }
  }
  scan_a[tid] = cgt; scan_b[tid] = ceq; __syncthreads();
  if (tid == 0) {
    int ag = 0, ae = 0;
    for (int i = 0; i < 256; i++) {
      int tg = scan_a[i], te = scan_b[i];
      scan_a[i] = ag; scan_b[i] = ae;
      ag += tg; ae += te;
    }
    sh[0] = ag; sh[1] = ae;
  }
  __syncthreads();
  int cnt_gt = sh[0], cnt_eq = sh[1];
  int og = scan_a[tid], oe = cnt_gt + scan_b[tid];
  for (int n = start; n < end; n++) {
    if (sel_mask(mode, n)) {
      unsigned k = __float_as_uint(g_max_vals[n]);
      if (k > kth) {
        out_idx[og] = n; out_valid[og] = 1;
        if (out_val) out_val[og] = g_max_vals[n];
        og++;
      } else if (k == kth) {
        if (oe < K) {
          out_idx[oe] = n; out_valid[oe] = 1;
          if (out_val) out_val[oe] = g_max_vals[n];
        }
        oe++;
      }
    }
  }
  int kmc = K - cnt_gt;
  int used = cnt_gt + (cnt_eq < kmc ? cnt_eq : kmc);
  __syncthreads();
  for (int i = used + tid; i < K; i += 256) {
    out_idx[i] = 0; out_valid[i] = 0;
    if (out_val) out_val[i] = -1.f;
  }
  __syncthreads();
}

__device__ void radix_select_list(const int* list, int count, int K,
                                  int* out_idx, int* out_valid, float* out_val,
                                  int* hist, int* scan_a, int* scan_b, int* sh) {
  // requires count > K
  int tid = threadIdx.x;
  unsigned prefix = 0; int rem = K;
  for (int pass = 0; pass < 4; pass++) {
    int shift = 24 - 8 * pass;
    hist[tid] = 0;
    __syncthreads();
    for (int i = tid; i < count; i += 256) {
      unsigned k = __float_as_uint(g_max_vals[list[i]]);
      if (pass == 0 || ((k >> (shift + 8)) == prefix))
        atomicAdd(&hist[(k >> shift) & 255], 1);
    }
    __syncthreads();
    if (tid == 0) {
      int cum = 0, b = 255;
      for (; b > 0; b--) {
        if (cum + hist[b] >= rem) break;
        cum += hist[b];
      }
      sh[0] = (int)((prefix << 8) | (unsigned)b);
      sh[1] = rem - cum;
    }
    __syncthreads();
    prefix = (unsigned)sh[0]; rem = sh[1];
    __syncthreads();
  }
  unsigned kth = prefix;
  int chunk = (count + 255) / 256;
  int start = tid * chunk; if (start > count) start = count;
  int end = start + chunk; if (end > count) end = count;
  int cgt = 0, ceq = 0;
  for (int i = start; i < end; i++) {
    unsigned k = __float_as_uint(g_max_vals[list[i]]);
    if (k > kth) cgt++;
    else if (k == kth) ceq++;
  }
  scan_a[tid] = cgt; scan_b[tid] = ceq; __syncthreads();
  if (tid == 0) {
    int ag = 0, ae = 0;
    for (int i = 0; i < 256; i++) {
      int tg = scan_a[i], te = scan_b[i];
      scan_a[i] = ag; scan_b[i] = ae;
      ag += tg; ae += te;
    }
    sh[0] = ag;
  }
  __syncthreads();
  int cnt_gt = sh[0];
  int og = scan_a[tid], oe = cnt_gt + scan_b[tid];
  for (int i = start; i < end; i++) {
    int n = list[i];
    unsigned k = __float_as_uint(g_max_vals[n]);
    if (k > kth) {
      out_idx[og] = n; out_valid[og] = 1;
      if (out_val) out_val[og] = g_max_vals[n];
      og++;
    } else if (k == kth) {
      if (oe < K) {
        out_idx[oe] = n; out_valid[oe] = 1;
        if (out_val) out_val[oe] = g_max_vals[n];
      }
      oe++;
    }
  }
  __syncthreads();
}

// block-local selection for the (rare) slow path; outputs to LDS arrays
__device__ void slow_select_lds(int tp, int thn, int fallback,
                                int* s_pidx, int* s_pvalid, float* s_pv,
                                int* s_hidx, int* s_hvalid,
                                int* hist, int* scan_a, int* scan_b, int* sh_i) {
  int tid = threadIdx.x;
  if (!fallback && tp <= KPOS) {
    for (int i = tid; i < KPOS; i += 256) {
      if (i < tp) {
        int m = g_pos_cand[i];
        s_pidx[i] = m; s_pvalid[i] = 1; s_pv[i] = g_max_vals[m];
      } else { s_pidx[i] = 0; s_pvalid[i] = 0; s_pv[i] = -1.f; }
    }
    __syncthreads();
  } else if (!fallback && tp <= CAP) {
    radix_select_list(g_pos_cand, tp, KPOS, s_pidx, s_pvalid, s_pv, hist, scan_a, scan_b, sh_i);
  } else if (!fallback) {
    radix_select_mask(MASK_POS, KPOS, s_pidx, s_pvalid, s_pv, hist, scan_a, scan_b, sh_i);
  } else {
    radix_select_mask(MASK_ALL, 10, s_pidx, s_pvalid, s_pv, hist, scan_a, scan_b, sh_i);
    for (int i = 10 + tid; i < KPOS; i += 256) {
      s_pidx[i] = 0; s_pvalid[i] = 0; s_pv[i] = -1.f;
    }
    __syncthreads();
  }
  if (thn <= KHN) {
    for (int i = tid; i < KHN; i += 256) {
      if (i < thn) { s_hidx[i] = g_hn_cand[i]; s_hvalid[i] = 1; }
      else { s_hidx[i] = 0; s_hvalid[i] = 0; }
    }
    __syncthreads();
  } else if (thn <= CAP) {
    radix_select_list(g_hn_cand, thn, KHN, s_hidx, s_hvalid, (float*)0, hist, scan_a, scan_b, sh_i);
  } else {
    radix_select_mask(MASK_HN, KHN, s_hidx, s_hvalid, (float*)0, hist, scan_a, scan_b, sh_i);
  }
}

// ---------------- decode helper ----------------
__device__ void decode_box(int n, const InPtrs& P, float* bb, float* cor,
                           float& area, float& scale, int& cls_out,
                           float* opx, float* opy) {
  int lvl, idx, hw; float px, py;
  point_info(n, lvl, idx, hw, px, py);
  const float* box = P.p[lvl * 4 + 1];
  const float* ang = P.p[lvl * 4 + 2];
  float l = box[idx], t = box[hw + idx], r = box[2 * hw + idx], b = box[3 * hw + idx];
  float a = ang[idx];
  float ca = cosf(a), sa = sinf(a);
  float w = l + r, h = t + b;
  float oxl = (r - l) * 0.5f, oyl = (b - t) * 0.5f;
  float ox = ca * oxl - sa * oyl;
  float oy = sa * oxl + ca * oyl;
  float an = mod_pos(a + HPI_F, PI_F) - HPI_F;
  float cx = px + ox, cy = py + oy;
  bb[0] = cx; bb[1] = cy; bb[2] = w; bb[3] = h; bb[4] = an;
  float c2 = cosf(an), s2 = sinf(an);
  const float dxs[4] = {-0.5f, 0.5f, 0.5f, -0.5f};
  const float dys[4] = {-0.5f, -0.5f, 0.5f, 0.5f};
#pragma unroll
  for (int k = 0; k < 4; k++) {
    float dx = dxs[k] * w, dy = dys[k] * h;
    cor[2 * k]     = cx + dx * c2 - dy * s2;
    cor[2 * k + 1] = cy + dx * s2 + dy * c2;
  }
  area = fabsf(w * h);
  scale = (float)lvl;
  cls_out = g_class_ind[n];
  if (opx) { *opx = px; *opy = py; }
}

__device__ void decode_to_pos_slot(int o, int n, const InPtrs& P) {
  float bb[5], cor[8], ar, sc; int cl;
  decode_box(n, P, bb, cor, ar, sc, cl, (float*)0, (float*)0);
#pragma unroll
  for (int k = 0; k < 5; k++) g_pos_bbox[o * 5 + k] = bb[k];
#pragma unroll
  for (int k = 0; k < 8; k++) g_pos_cor[o * 8 + k] = cor[k];
  g_pos_area[o] = ar; g_pos_scale[o] = sc; g_pos_class[o] = cl;
  g_pv[o] = g_max_vals[n];
}
__device__ void decode_to_hn_slot(int o, int n, const InPtrs& P) {
  float bb[5], cor[8], ar, sc, px, py; int cl;
  decode_box(n, P, bb, cor, ar, sc, cl, &px, &py);
#pragma unroll
  for (int k = 0; k < 8; k++) g_hn_cor[o * 8 + k] = cor[k];
  g_hn_area[o] = ar; g_hn_scale[o] = sc; g_hn_class[o] = cl;
  g_hn_px[o] = px; g_hn_py[o] = py;
}

// ---------------- convex quad intersection — fully register-resident ----------------
#define BPASS(KK, JJ)                                                      \
  _Pragma("unroll")                                                        \
  for (int i = 0; i < 32; i++) {                                           \
    int l = i ^ (JJ);                                                      \
    if (l > i) {                                                           \
      bool up = ((i & (KK)) == 0);                                         \
      float aa = sa_[i], ab = sa_[l];                                      \
      bool sw = up ? (aa > ab) : (aa < ab);                                \
      sa_[i] = sw ? ab : aa; sa_[l] = sw ? aa : ab;                        \
      float xi = sx_[i], xl = sx_[l];                                      \
      sx_[i] = sw ? xl : xi; sx_[l] = sw ? xi : xl;                        \
      float yi = sy_[i], yl = sy_[l];                                      \
      sy_[i] = sw ? yl : yi; sy_[l] = sw ? yi : yl;                        \
    }                                                                      \
  }

__device__ float inter_area(const float* __restrict__ A, const float* __restrict__ B) {
  float ax[4], ay[4], bx[4], by[4];
#pragma unroll
  for (int i = 0; i < 4; i++) {
    ax[i] = A[2 * i]; ay[i] = A[2 * i + 1];
    bx[i] = B[2 * i]; by[i] = B[2 * i + 1];
  }
  float dax[4], day[4], dbx[4], dby[4];
#pragma unroll
  for (int i = 0; i < 4; i++) {
    int i1 = (i + 1) & 3;
    dax[i] = ax[i1] - ax[i]; day[i] = ay[i1] - ay[i];
    dbx[i] = bx[i1] - bx[i]; dby[i] = by[i1] - by[i];
  }
  float px[24], py[24]; bool val[24];
#pragma unroll
  for (int i = 0; i < 4; i++) {
#pragma unroll
    for (int j = 0; j < 4; j++) {
      float dx = bx[j] - ax[i], dy = by[j] - ay[i];
      float den = crs(dax[i], day[i], dbx[j], dby[j]);
      float ad = fabsf(den);
      float ds = (ad < 1e-10f) ? 1.0f : den;
      float t = crs(dx, dy, dbx[j], dby[j]) / ds;
      float u = crs(dx, dy, dax[i], day[i]) / ds;
      bool ok = (ad > 1e-10f) & (t >= 0.f) & (t <= 1.f) & (u >= 0.f) & (u <= 1.f);
      int k = i * 4 + j;
      px[k] = ax[i] + t * dax[i];
      py[k] = ay[i] + t * day[i];
      val[k] = ok;
    }
  }
#pragma unroll
  for (int i = 0; i < 4; i++) {   // corners of A inside B
    bool ge = true, le = true;
#pragma unroll
    for (int j = 0; j < 4; j++) {
      float s = crs(dbx[j], dby[j], ax[i] - bx[j], ay[i] - by[j]);
      ge = ge && (s >= -1e-9f);
      le = le && (s <= 1e-9f);
    }
    val[16 + i] = ge || le; px[16 + i] = ax[i]; py[16 + i] = ay[i];
  }
#pragma unroll
  for (int j = 0; j < 4; j++) {   // corners of B inside A
    bool ge = true, le = true;
#pragma unroll
    for (int i = 0; i < 4; i++) {
      float s = crs(dax[i], day[i], bx[j] - ax[i], by[j] - ay[i]);
      ge = ge && (s >= -1e-9f);
      le = le && (s <= 1e-9f);
    }
    val[20 + j] = ge || le; px[20 + j] = bx[j]; py[20 + j] = by[j];
  }
  int n = 0; float sx = 0.f, sy = 0.f;
#pragma unroll
  for (int k = 0; k < 24; k++) if (val[k]) { n++; sx += px[k]; sy += py[k]; }
  float dn = (float)(n > 1 ? n : 1);
  float cx = sx / dn, cy = sy / dn;

  // 24 real slots (invalid collapse to centroid) + 8 +INF dummies; non-stable
  // network OK: angle ties only among identical centroid points (zero terms).
  float sa_[32], sx_[32], sy_[32];
#pragma unroll
  for (int k = 0; k < 24; k++) {
    float X = val[k] ? px[k] : cx;
    float Y = val[k] ? py[k] : cy;
    sx_[k] = X; sy_[k] = Y;
    sa_[k] = pseudo_ang(X - cx, Y - cy);
  }
#pragma unroll
  for (int k = 24; k < 32; k++) {
    sa_[k] = __int_as_float(0x7f800000);  // +inf
    sx_[k] = cx; sy_[k] = cy;
  }
  BPASS(2, 1)
  BPASS(4, 2)  BPASS(4, 1)
  BPASS(8, 4)  BPASS(8, 2)  BPASS(8, 1)
  BPASS(16, 8) BPASS(16, 4) BPASS(16, 2) BPASS(16, 1)
  BPASS(32, 16) BPASS(32, 8) BPASS(32, 4) BPASS(32, 2) BPASS(32, 1)

  float s2 = 0.f;
#pragma unroll
  for (int k = 0; k < 24; k++) {
    int k1 = (k + 1) % 24;
    s2 += crs(sx_[k] - cx, sy_[k] - cy, sx_[k1] - cx, sy_[k1] - cy);
  }
  float area = 0.5f * fabsf(s2);
  return (n >= 3) ? area : 0.f;
}

// ================= kernel 1: per-point stats + per-tile partials =================
__global__ __launch_bounds__(256) void k_prep(InPtrs P) {
  int tid = threadIdx.x;
  int t = blockIdx.x;
  int n = t * 256 + tid;
  __shared__ float r0[256], r1[256], r2[256];

  int lvl, idx, hw; float px, py;
  point_info(n, lvl, idx, hw, px, py);
  const float* cls = P.p[lvl * 4 + 0];
  const float* ctr = P.p[lvl * 4 + 3];
  float stiou = sigmoidf(ctr[idx]);
  float mv = -1.f, scm = 0.f; int ci = 0;
  for (int c = 0; c < NCLS; c++) {
    float sc = sigmoidf(cls[c * hw + idx]);
    if (sc > scm) scm = sc;
    float j = sc * stiou;
    if (j > mv) { mv = j; ci = c; }
  }
  g_max_vals[n] = mv;
  g_class_ind[n] = ci;
  g_sig_tiou[n] = stiou;
  g_sig_cls_max[n] = scm;
  g_hnflag[n] = 0;
  float isc = (mv >= 0.1f) ? 1.f : 0.f;
  r0[tid] = isc; r1[tid] = isc * mv; r2[tid] = isc * mv * mv;
  __syncthreads();
  for (int st = 128; st > 0; st >>= 1) {
    if (tid < st) { r0[tid] += r0[tid + st]; r1[tid] += r1[tid + st]; r2[tid] += r2[tid + st]; }
    __syncthreads();
  }
  if (tid == 0) {
    g_bcnt[t] = (int)r0[0];
    g_bsum[t] = r1[0];
    g_bsumsq[t] = r2[0];
  }
}

// ========== kernel 2: redundant threshold + masks + per-tile counts ==========
__global__ __launch_bounds__(256) void k_mask() {
  int tid = threadIdx.x;
  int t = blockIdx.x;
  int n = t * 256 + tid;
  __shared__ float s1[256], s2[256];
  __shared__ int s0[256];
  int c = 0; float s = 0.f, q = 0.f;
  for (int i = tid; i < TILES; i += 256) { c += g_bcnt[i]; s += g_bsum[i]; q += g_bsumsq[i]; }
  s0[tid] = c; s1[tid] = s; s2[tid] = q; __syncthreads();
  for (int st = 128; st > 0; st >>= 1) {
    if (tid < st) { s0[tid] += s0[tid + st]; s1[tid] += s1[tid + st]; s2[tid] += s2[tid + st]; }
    __syncthreads();
  }
  int nc = s0[0]; float sum = s1[0], sumsq = s2[0];
  float mean = sum / (float)(nc > 1 ? nc : 1);
  float E = sumsq - 2.f * mean * sum + (float)nc * mean * mean;
  if (E < 0.f) E = 0.f;
  float var = E / (float)((nc - 1) > 1 ? (nc - 1) : 1);
  float th = fminf(mean + sqrtf(var), 0.4f);
  if (nc == 0) th = __int_as_float(0x7f800000);  // +inf
  if (t == 0 && tid == 0) g_thresh = th;

  float v = g_max_vals[n];
  int pm = (v >= th) ? 1 : 0;
  int hm = (v >= 0.1f && v < th) ? 1 : 0;
  g_pos_mask[n] = pm; g_hn_mask[n] = hm;
  __syncthreads();
  __shared__ int t0[256], t1[256];
  t0[tid] = pm; t1[tid] = hm; __syncthreads();
  for (int st = 128; st > 0; st >>= 1) {
    if (tid < st) { t0[tid] += t0[tid + st]; t1[tid] += t1[tid + st]; }
    __syncthreads();
  }
  if (tid == 0) { g_bpos[t] = t0[0]; g_bhn[t] = t1[0]; }
}

// ========== kernel 3: offsets (per-block recompute) + compact + inline decode; tile 340 publishes totals ==========
__global__ __launch_bounds__(256) void k_compact(InPtrs P) {
  int tid = threadIdx.x;
  int t = blockIdx.x;
  int n = t * 256 + tid;
  __shared__ int si0[256], si1[256];

  // this block's exclusive offset (sum of counts of tiles < t)
  int cp = 0, ch = 0;
  for (int i = tid; i < t; i += 256) { cp += g_bpos[i]; ch += g_bhn[i]; }
  si0[tid] = cp; si1[tid] = ch; __syncthreads();
  for (int st = 128; st > 0; st >>= 1) {
    if (tid < st) { si0[tid] += si0[tid + st]; si1[tid] += si1[tid + st]; }
    __syncthreads();
  }
  int poff = si0[0], hoff = si1[0];
  __syncthreads();

  // in-tile inclusive scan of masks
  int pm = g_pos_mask[n], hm = g_hn_mask[n];
  si0[tid] = pm; si1[tid] = hm; __syncthreads();
  for (int off = 1; off < 256; off <<= 1) {
    int ap = (tid >= off) ? si0[tid - off] : 0;
    int ah = (tid >= off) ? si1[tid - off] : 0;
    __syncthreads();
    si0[tid] += ap; si1[tid] += ah;
    __syncthreads();
  }
  if (pm) {
    int o = poff + si0[tid] - pm;
    if (o < CAP) g_pos_cand[o] = n;
    if (o < KPOS) decode_to_pos_slot(o, n, P);
  }
  if (hm) {
    int o = hoff + si1[tid] - hm;
    if (o < CAP) g_hn_cand[o] = n;
    if (o < KHN) decode_to_hn_slot(o, n, P);
  }
  // tile 340 publishes totals + slow flag (plain stores; kernel boundary = fence)
  if (t == TILES - 1 && tid == 255) {
    int tp = poff + si0[255];
    int thn = hoff + si1[255];
    g_tp = tp; g_thn = thn;
    g_slow = (tp == 0 || tp > KPOS || thn > KHN) ? 1 : 0;
  }
}

// ============ kernel 4: IoU + aggregation + scatter (fast: dense inter_area; slow: block-local select) ============
__global__ __launch_bounds__(256) void k_iou(InPtrs P) {
  const int h = blockIdx.x;
  const int j = threadIdx.x;
  const int slow = g_slow;
  const int tp = g_tp, thn = g_thn;

  __shared__ float rw[7][256];
  __shared__ int lst[256], scn[256];
  // slow-path block-local buffers (unused on fast path)
  __shared__ int   s_pidx[KPOS], s_pvalid[KPOS];
  __shared__ float s_pv[KPOS];
  __shared__ int   s_hidx[KHN], s_hvalid[KHN];
  __shared__ int   hist[256], sca[256], scb[256], sh_i[2];

  int nh;
  float hcor[8], har, hsc, hpx, hpy; int hcl;

  if (!slow) {
    // ---------------- fast path (identical to passing R11) ----------------
    const int hv = (h < thn) ? 1 : 0;
    if (!hv) return;   // block-uniform
    nh = g_hn_cand[h];
#pragma unroll
    for (int k = 0; k < 8; k++) hcor[k] = g_hn_cor[h * 8 + k];
    har = g_hn_area[h]; hsc = g_hn_scale[h];
    hpx = g_hn_px[h]; hpy = g_hn_py[h];
    hcl = g_hn_class[h];

    // phase 1: cheap prefilter per positive slot j
    const int pvld = (j < tp) ? 1 : 0;
    bool pre = false;
    if (pvld) {
      pre = (g_pos_class[j] == hcl) && (fabsf(g_pos_scale[j] - hsc) <= 1.0f);
      if (pre) {
        float cx = g_pos_bbox[j * 5 + 0], cy = g_pos_bbox[j * 5 + 1];
        float bw = g_pos_bbox[j * 5 + 2], bh = g_pos_bbox[j * 5 + 3];
        float an = g_pos_bbox[j * 5 + 4];
        float ca = cosf(an), sa = sinf(an);
        float dx = hpx - cx, dy = hpy - cy;
        float ox = ca * dx + sa * dy, oy = -sa * dx + ca * dy;
        float mm = fminf(fminf(bw * 0.5f + ox, bw * 0.5f - ox),
                         fminf(bh * 0.5f + oy, bh * 0.5f - oy));
        pre = (mm > 0.f);
      }
    }

    // phase 2: index-compact surviving j's, run inter_area densely
    scn[j] = pre ? 1 : 0;
#pragma unroll
    for (int k = 0; k < 7; k++) rw[k][j] = 0.f;
    __syncthreads();
    for (int off = 1; off < 256; off <<= 1) {
      int a = (j >= off) ? scn[j - off] : 0;
      __syncthreads();
      scn[j] += a;
      __syncthreads();
    }
    if (pre) lst[scn[j] - 1] = j;
    int nv = scn[255];
    __syncthreads();

    for (int i = j; i < nv; i += 256) {
      int jj = lst[i];
      float pcor[8];
#pragma unroll
      for (int k = 0; k < 8; k++) pcor[k] = g_pos_cor[jj * 8 + k];
      float inter = inter_area(hcor, pcor);
      float iou = inter / (har + g_pos_area[jj] - inter + 1e-8f);
      if (iou >= 0.6f) {
        float pv = g_pv[jj];
        rw[0][jj] = pv;
#pragma unroll
        for (int k = 0; k < 5; k++) rw[1 + k][jj] = pv * g_pos_bbox[jj * 5 + k];
        rw[6][jj] = 1.f;
      }
    }
    __syncthreads();
  } else {
    // ---------------- slow path (rare): block-local select + in-register decode ----------------
    const int fallback = (tp == 0) ? 1 : 0;
    slow_select_lds(tp, thn, fallback, s_pidx, s_pvalid, s_pv, s_hidx, s_hvalid,
                    hist, sca, scb, sh_i);
    // fallback: publish top-10 as positives for k_loss (block 0 only; boundary orders it)
    if (fallback && h == 0) {
      for (int i = j; i < 10; i += 256)
        if (s_pvalid[i]) g_pos_mask[s_pidx[i]] = 1;
    }
    const int hv = s_hvalid[h];
    if (!hv) return;   // block-uniform
    nh = s_hidx[h];
    {
      float hbb[5]; float ar, sc; int cl;
      decode_box(nh, P, hbb, hcor, ar, sc, cl, &hpx, &hpy);
      har = ar; hsc = sc; hcl = cl;
    }
#pragma unroll
    for (int k = 0; k < 7; k++) rw[k][j] = 0.f;
    __syncthreads();
    if (s_pvalid[j]) {
      int m = s_pidx[j];
      float pv = s_pv[j];
      float pbb[5], pcor[8], par, psc; int pcl;
      decode_box(m, P, pbb, pcor, par, psc, pcl, (float*)0, (float*)0);
      bool valid = (pcl == hcl) && (fabsf(psc - hsc) <= 1.0f);
      if (valid) {
        float ca = cosf(pbb[4]), sa = sinf(pbb[4]);
        float dx = hpx - pbb[0], dy = hpy - pbb[1];
        float ox = ca * dx + sa * dy, oy = -sa * dx + ca * dy;
        float mm = fminf(fminf(pbb[2] * 0.5f + ox, pbb[2] * 0.5f - ox),
                         fminf(pbb[3] * 0.5f + oy, pbb[3] * 0.5f - oy));
        valid = (mm > 0.f);
      }
      if (valid) {
        float inter = inter_area(hcor, pcor);
        float iou = inter / (har + par - inter + 1e-8f);
        valid = (iou >= 0.6f);
      }
      if (valid) {
        rw[0][j] = pv;
#pragma unroll
        for (int k = 0; k < 5; k++) rw[1 + k][j] = pv * pbb[k];
        rw[6][j] = 1.f;
      }
    }
    __syncthreads();
  }

  // common: j-ordered tree reduction + writeback
  for (int st = 128; st > 0; st >>= 1) {
    if (j < st)
#pragma unroll
      for (int k = 0; k < 7; k++) rw[k][j] += rw[k][j + st];
    __syncthreads();
  }
  if (j == 0 && rw[6][0] > 0.f) {
    float inv = 1.f / fmaxf(rw[0][0], 1e-8f);
    float bb[5];
#pragma unroll
    for (int k = 0; k < 5; k++) bb[k] = rw[1 + k][0] * inv;
    float ca = cosf(bb[4]), sa = sinf(bb[4]);
    float dx = hpx - bb[0], dy = hpy - bb[1];
    float ox = ca * dx + sa * dy, oy = -sa * dx + ca * dy;
    g_loc_targets[nh * 5 + 0] = bb[2] * 0.5f + ox;
    g_loc_targets[nh * 5 + 1] = bb[3] * 0.5f + oy;
    g_loc_targets[nh * 5 + 2] = bb[2] * 0.5f - ox;
    g_loc_targets[nh * 5 + 3] = bb[3] * 0.5f - oy;
    g_loc_targets[nh * 5 + 4] = bb[4];
    g_hnflag[nh] = 1;
  }
}

// ============ kernel 5: per-point losses -> per-tile partials ============
__global__ __launch_bounds__(256) void k_loss(InPtrs P) {
  int tid = threadIdx.x;
  int t = blockIdx.x;
  int n = t * 256 + tid;
  __shared__ float red[6][256];
  float v0, v1, v2, v3, v4, v5;
  {
    int lvl, idx, hw; float px, py;
    point_info(n, lvl, idx, hw, px, py);
    int pm = g_pos_mask[n], hm = g_hn_mask[n], hf = g_hnflag[n];
    int sel = pm | hm;
    bool lp = (pm | hf) != 0;
    float ctmax = sel ? g_sig_cls_max[n] : 0.f;
    const float* tcls = P.p[lvl * 4 + 0];
    const float* tbox = P.p[lvl * 4 + 1];
    const float* tang = P.p[lvl * 4 + 2];
    const float* scls = P.p[20 + lvl * 4 + 0];
    const float* sbox = P.p[20 + lvl * 4 + 1];
    const float* sang = P.p[20 + lvl * 4 + 2];
    const float* sctr = P.p[20 + lvl * 4 + 3];
    float siou = sigmoidf(sctr[idx]);
    float scl = 0.f;
    for (int c = 0; c < NCLS; c++) {
      float jc = sigmoidf(scls[c * hw + idx]) * siou;
      float ct = sel ? sigmoidf(tcls[c * hw + idx]) : 0.f;
      float p = jc;
      if (p < 1e-12f) p = 1e-12f;
      float pu = 1.f - 1e-12f;
      if (p > pu) p = pu;
      float bce = -(ct * logf(p) + (1.f - ct) * log1pf(-p));
      float d = fabsf(jc - ct);
      scl += bce * d * d;
    }
    v0 = scl;
    float lw = lp ? ctmax : 0.f;
    float tgt[5];
    if (hf) {
#pragma unroll
      for (int k = 0; k < 5; k++) tgt[k] = g_loc_targets[n * 5 + k];
    } else if (pm) {
      tgt[0] = tbox[idx]; tgt[1] = tbox[hw + idx];
      tgt[2] = tbox[2 * hw + idx]; tgt[3] = tbox[3 * hw + idx];
      tgt[4] = tang[idx];
    } else {
#pragma unroll
      for (int k = 0; k < 5; k++) tgt[k] = 0.f;
    }
    float sb = 0.f;
#pragma unroll
    for (int k = 0; k < 5; k++) {
      float sv = (k < 4) ? sbox[k * hw + idx] : sang[idx];
      float d = fabsf(sv - tgt[k]);
      sb += (d < 1.f) ? 0.5f * d * d : d - 0.5f;
    }
    v1 = sb * lw;
    v2 = 0.f;
    if (lp) {
      float p = siou;
      if (p < 1e-12f) p = 1e-12f;
      float pu = 1.f - 1e-12f;
      if (p > pu) p = pu;
      float ti = g_sig_tiou[n];
      v2 = -(ti * logf(p) + (1.f - ti) * log1pf(-p));
    }
    v3 = pm ? ctmax : 0.f;   // cls_avg
    v4 = lw;                 // loc_avg
    v5 = lp ? 1.f : 0.f;     // iou_avg
  }
  red[0][tid] = v0; red[1][tid] = v1; red[2][tid] = v2;
  red[3][tid] = v3; red[4][tid] = v4; red[5][tid] = v5;
  __syncthreads();
  for (int st = 128; st > 0; st >>= 1) {
    if (tid < st)
#pragma unroll
      for (int k = 0; k < 6; k++) red[k][tid] += red[k][tid + st];
    __syncthreads();
  }
  if (tid == 0)
#pragma unroll
    for (int k = 0; k < 6; k++) g_partials[t * 6 + k] = red[k][0];
}

// ============ kernel 6: final reduce + output ============
__global__ __launch_bounds__(256) void k_final(float* out) {
  int tid = threadIdx.x;
  float a[6] = {0,0,0,0,0,0};
  for (int b = tid; b < TILES; b += 256)
#pragma unroll
    for (int k = 0; k < 6; k++) a[k] += g_partials[b * 6 + k];
  __shared__ float red[6][256];
#pragma unroll
  for (int k = 0; k < 6; k++) red[k][tid] = a[k];
  __syncthreads();
  for (int st = 128; st > 0; st >>= 1) {
    if (tid < st)
#pragma unroll
      for (int k = 0; k < 6; k++) red[k][tid] += red[k][tid + st];
    __syncthreads();
  }
  if (tid == 0) {
    out[0] = red[0][0] / fmaxf(red[3][0], 1e-8f);
    out[1] = red[1][0] / fmaxf(red[4][0], 1e-8f);
    out[2] = red[2][0] / fmaxf(red[5][0], 1.f);
  }
}

extern "C" void kernel_launch(void* const* d_in, const int* in_sizes, int n_in,
                              void* d_out, int out_size, void* d_ws, size_t ws_size,
                              hipStream_t stream) {
  (void)in_sizes; (void)n_in; (void)out_size; (void)d_ws; (void)ws_size;
  InPtrs P;
  for (int i = 0; i < 40; i++) P.p[i] = (const float*)d_in[i];
  k_prep<<<TILES, 256, 0, stream>>>(P);
  k_mask<<<TILES, 256, 0, stream>>>();
  k_compact<<<TILES, 256, 0, stream>>>(P);
  k_iou<<<KHN, 256, 0, stream>>>(P);
  k_loss<<<TILES, 256, 0, stream>>>(P);
  k_final<<<1, 256, 0, stream>>>((float*)d_out);
}